// Round 1
// baseline (432.304 us; speedup 1.0000x reference)
//
#include <hip/hip_runtime.h>

#define NN 2048
#define NH 8

// ---------------------------------------------------------------------------
// Kernel A: per-node projections into workspace.
// kfeat[h][n][80]  : [0..31]=ak_i, [32+i*3+v]=vk_{i,v}
// qfeat[h][m][80]  : same layout with aq/vq
// valfeat[h][n][96]: [0..15]=aval, [16+i*3+v]=vval, [40+i*3+v]=v2a, [88+i]=a2v
// 256 blocks x 256 threads, 8 nodes per block; 2048 dot-rows shared across
// the 8 nodes (weight row read once, applied to 8 LDS-staged nodes).
// ---------------------------------------------------------------------------
__global__ __launch_bounds__(256) void proj_kernel(
    const float* __restrict__ ax, const float* __restrict__ vx,
    const float* __restrict__ W_ak, const float* __restrict__ W_vk,
    const float* __restrict__ W_aq, const float* __restrict__ W_vq,
    const float* __restrict__ W_aval, const float* __restrict__ W_vval,
    const float* __restrict__ W_a2vval, const float* __restrict__ W_v2aval,
    float* __restrict__ kfeat, float* __restrict__ qfeat,
    float* __restrict__ valfeat)
{
    __shared__ float axs[8][128];
    __shared__ float vxs[3][8][64];   // [v][node][chan] so v-rows read float4
    const int t  = threadIdx.x;
    const int n0 = blockIdx.x * 8;

    for (int idx = t; idx < 8 * 128; idx += 256)
        axs[idx >> 7][idx & 127] = ax[n0 * 128 + idx];
    for (int idx = t; idx < 8 * 192; idx += 256) {
        int nb = idx / 192, r = idx - nb * 192;
        int j = r / 3, v = r - j * 3;
        vxs[v][nb][j] = vx[n0 * 192 + idx];
    }
    __syncthreads();

    #pragma unroll 1
    for (int rr = 0; rr < 8; ++rr) {
        int r = rr * 256 + t;
        const float* wrow; float* dst;
        int len, v = 0, stride, col, h; bool isA;
        if (r < 256)       { int q = r;        h = q >> 5; wrow = W_ak     + q * 128;               len = 128; isA = true;  dst = kfeat;   stride = 80; col = q & 31; }
        else if (r < 512)  { int q = r - 256;  h = q >> 5; wrow = W_aq     + q * 128;               len = 128; isA = true;  dst = qfeat;   stride = 80; col = q & 31; }
        else if (r < 896)  { int q = r - 512;  h = q / 48; int s = q - h * 48; v = s % 3; wrow = W_vk     + (h * 16 + s / 3) * 64; len = 64; isA = false; dst = kfeat;   stride = 80; col = 32 + s; }
        else if (r < 1280) { int q = r - 896;  h = q / 48; int s = q - h * 48; v = s % 3; wrow = W_vq     + (h * 16 + s / 3) * 64; len = 64; isA = false; dst = qfeat;   stride = 80; col = 32 + s; }
        else if (r < 1408) { int q = r - 1280; h = q >> 4; wrow = W_aval   + q * 128;               len = 128; isA = true;  dst = valfeat; stride = 96; col = q & 15; }
        else if (r < 1600) { int q = r - 1408; h = q / 24; int s = q - h * 24; v = s % 3; wrow = W_vval   + (h * 8  + s / 3) * 64; len = 64; isA = false; dst = valfeat; stride = 96; col = 16 + s; }
        else if (r < 1984) { int q = r - 1600; h = q / 48; int s = q - h * 48; v = s % 3; wrow = W_v2aval + (h * 16 + s / 3) * 64; len = 64; isA = false; dst = valfeat; stride = 96; col = 40 + s; }
        else               { int q = r - 1984; h = q >> 3; wrow = W_a2vval + q * 128;               len = 128; isA = true;  dst = valfeat; stride = 96; col = 88 + (q & 7); }

        float acc[8] = {0.f, 0.f, 0.f, 0.f, 0.f, 0.f, 0.f, 0.f};
        if (isA) {
            for (int j = 0; j < 128; j += 4) {
                float4 w4 = *(const float4*)(wrow + j);
                #pragma unroll
                for (int nb = 0; nb < 8; ++nb) {
                    float4 x4 = *(const float4*)(&axs[nb][j]);
                    acc[nb] += w4.x * x4.x + w4.y * x4.y + w4.z * x4.z + w4.w * x4.w;
                }
            }
        } else {
            for (int j = 0; j < 64; j += 4) {
                float4 w4 = *(const float4*)(wrow + j);
                #pragma unroll
                for (int nb = 0; nb < 8; ++nb) {
                    float4 x4 = *(const float4*)(&vxs[v][nb][j]);
                    acc[nb] += w4.x * x4.x + w4.y * x4.y + w4.z * x4.z + w4.w * x4.w;
                }
            }
        }
        #pragma unroll
        for (int nb = 0; nb < 8; ++nb)
            dst[((size_t)h * NN + n0 + nb) * stride + col] = acc[nb];
    }
}

// ---------------------------------------------------------------------------
// Kernel B: attention + value mixing + epilogue, fused.
// Grid: 32 m-tiles x 8 heads = 256 blocks; block = 512 threads = 8 waves.
// Lane = one query m (qfeat + 40 accumulators in VGPRs); wave = one 256-key
// segment. Key-side data is wave-uniform -> scalar loads / L1 broadcast.
// p = prox * exp(0.1*dot): no max tracking (dot ~ 1e-2 by construction),
// partials combine additively across waves via LDS tree.
// ---------------------------------------------------------------------------
__global__ __launch_bounds__(512) void attn_kernel(
    const float* __restrict__ kfeat, const float* __restrict__ qfeat,
    const float* __restrict__ valfeat, const float* __restrict__ pos_k,
    const float* __restrict__ pos_q, const float* __restrict__ r0,
    float* __restrict__ out)
{
    const int mt   = blockIdx.x >> 3;
    const int h    = blockIdx.x & 7;
    const int lane = threadIdx.x & 63;
    const int wid  = threadIdx.x >> 6;
    const int m    = mt * 64 + lane;

    const float r0h  = r0[h];
    const float r0sq = r0h * r0h;

    float qf[80];
    {
        const float4* qp = (const float4*)(qfeat + ((size_t)h * NN + m) * 80);
        #pragma unroll
        for (int j = 0; j < 20; ++j) {
            float4 v4 = qp[j];
            qf[4 * j] = v4.x; qf[4 * j + 1] = v4.y; qf[4 * j + 2] = v4.z; qf[4 * j + 3] = v4.w;
        }
    }
    const float pkx = pos_k[m * 3], pky = pos_k[m * 3 + 1], pkz = pos_k[m * 3 + 2];

    float denom = 0.f, aa[16], av[24];
    #pragma unroll
    for (int i = 0; i < 16; ++i) aa[i] = 0.f;
    #pragma unroll
    for (int i = 0; i < 24; ++i) av[i] = 0.f;

    const int wseg = __builtin_amdgcn_readfirstlane(wid);  // uniform -> scalar key loads
    const float* kfb = kfeat   + ((size_t)h * NN + wseg * 256) * 80;
    const float* vfb = valfeat + ((size_t)h * NN + wseg * 256) * 96;
    const float* pqb = pos_q + wseg * 256 * 3;

    for (int k = 0; k < 256; ++k) {
        const float* kf = kfb + k * 80;
        const float* vf = vfb + k * 96;
        float pqx = pqb[k * 3], pqy = pqb[k * 3 + 1], pqz = pqb[k * 3 + 2];
        float sx = pkx - pqx, sy = pky - pqy, sz = pkz - pqz;
        float d2 = sx * sx + sy * sy + sz * sz;

        float s0 = 0.f, s1 = 0.f, s2 = 0.f, s3 = 0.f;
        #pragma unroll
        for (int j = 0; j < 80; j += 4) {
            s0 += kf[j]     * qf[j];
            s1 += kf[j + 1] * qf[j + 1];
            s2 += kf[j + 2] * qf[j + 2];
            s3 += kf[j + 3] * qf[j + 3];
        }
        float dt = (s0 + s1) + (s2 + s3);

        float tt = 1.0f / (r0sq + d2);
        float p  = r0sq * tt * __expf(0.1f * dt);   // = prox * exp(scaled dot)
        float ps = p * sqrtf(tt);                    // p * sqrt(prox/r0^2)
        float gx = ps * sx, gy = ps * sy, gz = ps * sz;
        denom += p;

        #pragma unroll
        for (int i = 0; i < 16; ++i)
            aa[i] += p * vf[i] + gx * vf[40 + 3 * i] + gy * vf[41 + 3 * i] + gz * vf[42 + 3 * i];
        #pragma unroll
        for (int q = 0; q < 24; ++q)
            av[q] += p * vf[16 + q];
        #pragma unroll
        for (int i = 0; i < 8; ++i) {
            float a2 = vf[88 + i];
            av[3 * i] += gx * a2; av[3 * i + 1] += gy * a2; av[3 * i + 2] += gz * a2;
        }
    }

    // ---- cross-wave tree reduction (8 -> 4 -> 2 -> 1) ----
    __shared__ float red[4][64][42];
    float my[41];
    my[0] = denom;
    #pragma unroll
    for (int i = 0; i < 16; ++i) my[1 + i] = aa[i];
    #pragma unroll
    for (int q = 0; q < 24; ++q) my[17 + q] = av[q];

    if (wid >= 4) {
        float* rp = &red[wid - 4][lane][0];
        #pragma unroll
        for (int i = 0; i < 41; ++i) rp[i] = my[i];
    }
    __syncthreads();
    if (wid < 4) {
        const float* rp = &red[wid][lane][0];
        #pragma unroll
        for (int i = 0; i < 41; ++i) my[i] += rp[i];
    }
    __syncthreads();
    if (wid == 2 || wid == 3) {
        float* rp = &red[wid - 2][lane][0];
        #pragma unroll
        for (int i = 0; i < 41; ++i) rp[i] = my[i];
    }
    __syncthreads();
    if (wid < 2) {
        const float* rp = &red[wid][lane][0];
        #pragma unroll
        for (int i = 0; i < 41; ++i) my[i] += rp[i];
    }
    __syncthreads();
    if (wid == 1) {
        float* rp = &red[0][lane][0];
        #pragma unroll
        for (int i = 0; i < 41; ++i) rp[i] = my[i];
    }
    __syncthreads();
    if (wid == 0) {
        const float* rp = &red[0][lane][0];
        #pragma unroll
        for (int i = 0; i < 41; ++i) my[i] += rp[i];
        float inv = 1.0f / my[0];
        float* oa = out + (size_t)m * 128 + h * 16;
        #pragma unroll
        for (int i = 0; i < 16; ++i) oa[i] = my[1 + i] * inv;
        float* ov = out + (size_t)NN * 128 + (size_t)m * 192 + h * 24;
        #pragma unroll
        for (int q = 0; q < 24; ++q) ov[q] = my[17 + q] * inv;
    }
}

extern "C" void kernel_launch(void* const* d_in, const int* in_sizes, int n_in,
                              void* d_out, int out_size, void* d_ws, size_t ws_size,
                              hipStream_t stream) {
    const float* ax       = (const float*)d_in[0];
    const float* vx       = (const float*)d_in[1];
    const float* pos_k    = (const float*)d_in[2];
    const float* pos_q    = (const float*)d_in[3];
    const float* r0       = (const float*)d_in[4];
    const float* W_ak     = (const float*)d_in[5];
    const float* W_vk     = (const float*)d_in[6];
    const float* W_aq     = (const float*)d_in[7];
    const float* W_vq     = (const float*)d_in[8];
    const float* W_aval   = (const float*)d_in[9];
    const float* W_vval   = (const float*)d_in[10];
    const float* W_a2vval = (const float*)d_in[11];
    const float* W_v2aval = (const float*)d_in[12];

    float* ws      = (float*)d_ws;
    float* kfeat   = ws;                               // 8*2048*80
    float* qfeat   = ws + (size_t)NH * NN * 80;        // 8*2048*80
    float* valfeat = ws + (size_t)2 * NH * NN * 80;    // 8*2048*96
    float* outp    = (float*)d_out;

    hipLaunchKernelGGL(proj_kernel, dim3(NN / 8), dim3(256), 0, stream,
                       ax, vx, W_ak, W_vk, W_aq, W_vq, W_aval, W_vval,
                       W_a2vval, W_v2aval, kfeat, qfeat, valfeat);
    hipLaunchKernelGGL(attn_kernel, dim3(32 * NH), dim3(512), 0, stream,
                       kfeat, qfeat, valfeat, pos_k, pos_q, r0, outp);
}

// Round 2
// 174.910 us; speedup vs baseline: 2.4716x; 2.4716x over previous
//
#include <hip/hip_runtime.h>

#define NN 2048
#define NH 8

typedef __attribute__((ext_vector_type(4))) short s4;
typedef __attribute__((ext_vector_type(4))) float f4;

static __device__ __forceinline__ ushort f2b(float x) {
    uint u = __builtin_bit_cast(uint, x);
    uint r = (u + 0x7FFFu + ((u >> 16) & 1u)) >> 16;
    return (ushort)r;
}
static __device__ __forceinline__ float b2f(ushort b) {
    return __builtin_bit_cast(float, ((uint)b) << 16);
}
static __device__ __forceinline__ uint cvtpk(float lo, float hi) {
    uint r;
    asm("v_cvt_pk_bf16_f32 %0, %1, %2" : "=v"(r) : "v"(lo), "v"(hi));
    return r;
}
static __device__ __forceinline__ s4 pack4(float a, float b, float c, float d) {
    uint2 w; w.x = cvtpk(a, b); w.y = cvtpk(c, d);
    return __builtin_bit_cast(s4, w);
}
static __device__ __forceinline__ f4 mfma16(s4 a, s4 b, f4 c) {
#if __has_builtin(__builtin_amdgcn_mfma_f32_16x16x16bf16_1k)
    return __builtin_amdgcn_mfma_f32_16x16x16bf16_1k(a, b, c, 0, 0, 0);
#else
    asm volatile("v_mfma_f32_16x16x16_bf16 %0, %1, %2, %0" : "+v"(c) : "v"(a), "v"(b));
    return c;
#endif
}

// ---------------------------------------------------------------------------
// Kernel A: per-node projections -> bf16 feature arrays.
// Kf[h][n][128]: [0..31]=ak, [32+i*3+v]=vk, [80..95]=0, [96..111]=d2 key slots,
//                [112..127]=0        (slots filled by finish_kernel)
// Qf[h][m][128]: same with 0.1*aq, 0.1*vq; d2 query slots
// Vt[h][144][2048] (feature-major): [0..15]=aval, [16+s]=vval, [40]=1, [41..47]=0,
//   [48+s]=v2a, [96+i]=w_i, [112+i']=a2v, [120+3i'+v]=a2v*pos_q_v
// ---------------------------------------------------------------------------
__global__ __launch_bounds__(256) void proj_kernel(
    const float* __restrict__ ax, const float* __restrict__ vx,
    const float* __restrict__ W_ak, const float* __restrict__ W_vk,
    const float* __restrict__ W_aq, const float* __restrict__ W_vq,
    const float* __restrict__ W_aval, const float* __restrict__ W_vval,
    const float* __restrict__ W_a2vval, const float* __restrict__ W_v2aval,
    ushort* __restrict__ Kf, ushort* __restrict__ Qf, ushort* __restrict__ Vt)
{
    __shared__ float axs[8][128];
    __shared__ float vxs[3][8][64];
    const int t  = threadIdx.x;
    const int n0 = blockIdx.x * 8;

    for (int idx = t; idx < 8 * 128; idx += 256)
        axs[idx >> 7][idx & 127] = ax[n0 * 128 + idx];
    for (int idx = t; idx < 8 * 192; idx += 256) {
        int nb = idx / 192, r = idx - nb * 192;
        int j = r / 3, v = r - j * 3;
        vxs[v][nb][j] = vx[n0 * 192 + idx];
    }
    __syncthreads();

    #pragma unroll 1
    for (int rr = 0; rr < 8; ++rr) {
        int r = rr * 256 + t;
        const float* wrow; int h, v = 0, col = 0, vrow = -1; bool isA;
        float scale = 1.0f; ushort* dst = nullptr;
        if (r < 256)       { int q = r;        h = q >> 5; wrow = W_ak     + q * 128;               isA = true;  dst = Kf; col = q & 31; }
        else if (r < 512)  { int q = r - 256;  h = q >> 5; wrow = W_aq     + q * 128;               isA = true;  dst = Qf; col = q & 31; scale = 0.1f; }
        else if (r < 896)  { int q = r - 512;  h = q / 48; int s = q - h * 48; v = s % 3; wrow = W_vk     + (h * 16 + s / 3) * 64; isA = false; dst = Kf; col = 32 + s; }
        else if (r < 1280) { int q = r - 896;  h = q / 48; int s = q - h * 48; v = s % 3; wrow = W_vq     + (h * 16 + s / 3) * 64; isA = false; dst = Qf; col = 32 + s; scale = 0.1f; }
        else if (r < 1408) { int q = r - 1280; h = q >> 4; wrow = W_aval   + q * 128;               isA = true;  vrow = q & 15; }
        else if (r < 1600) { int q = r - 1408; h = q / 24; int s = q - h * 24; v = s % 3; wrow = W_vval   + (h * 8  + s / 3) * 64; isA = false; vrow = 16 + s; }
        else if (r < 1984) { int q = r - 1600; h = q / 48; int s = q - h * 48; v = s % 3; wrow = W_v2aval + (h * 16 + s / 3) * 64; isA = false; vrow = 48 + s; }
        else               { int q = r - 1984; h = q >> 3; wrow = W_a2vval + q * 128;               isA = true;  vrow = 112 + (q & 7); }

        float acc[8] = {0.f, 0.f, 0.f, 0.f, 0.f, 0.f, 0.f, 0.f};
        if (isA) {
            for (int j = 0; j < 128; j += 4) {
                float4 w4 = *(const float4*)(wrow + j);
                #pragma unroll
                for (int nb = 0; nb < 8; ++nb) {
                    float4 x4 = *(const float4*)(&axs[nb][j]);
                    acc[nb] += w4.x * x4.x + w4.y * x4.y + w4.z * x4.z + w4.w * x4.w;
                }
            }
        } else {
            for (int j = 0; j < 64; j += 4) {
                float4 w4 = *(const float4*)(wrow + j);
                #pragma unroll
                for (int nb = 0; nb < 8; ++nb) {
                    float4 x4 = *(const float4*)(&vxs[v][nb][j]);
                    acc[nb] += w4.x * x4.x + w4.y * x4.y + w4.z * x4.z + w4.w * x4.w;
                }
            }
        }
        #pragma unroll
        for (int nb = 0; nb < 8; ++nb) {
            ushort bv = f2b(scale * acc[nb]);
            if (vrow >= 0) Vt[((size_t)h * 144 + vrow) * NN + n0 + nb] = bv;
            else           dst[((size_t)h * NN + n0 + nb) * 128 + col] = bv;
        }
    }
}

// ---------------------------------------------------------------------------
// Kernel B: derived features + d2 slots + pads. Thread per (h, n).
// d2 = |pq|^2 + |pk|^2 - 2 pk.pq via split-bf16 slot products.
// ---------------------------------------------------------------------------
__global__ __launch_bounds__(256) void finish_kernel(
    const float* __restrict__ pos_k, const float* __restrict__ pos_q,
    ushort* __restrict__ Kf, ushort* __restrict__ Qf, ushort* __restrict__ Vt)
{
    int g = blockIdx.x * 256 + threadIdx.x;   // 0..16383
    int h = g >> 11, n = g & 2047;
    float pqx = pos_q[n * 3], pqy = pos_q[n * 3 + 1], pqz = pos_q[n * 3 + 2];
    float pkx = pos_k[n * 3], pky = pos_k[n * 3 + 1], pkz = pos_k[n * 3 + 2];

    ushort* Ko = Kf + ((size_t)h * NN + n) * 128;
    ushort* Qo = Qf + ((size_t)h * NN + n) * 128;
    #pragma unroll
    for (int j = 80; j < 96; ++j) { Ko[j] = 0; Qo[j] = 0; }
    #pragma unroll
    for (int j = 112; j < 128; ++j) { Ko[j] = 0; Qo[j] = 0; }

    // K-side slots (pos_q of key node)
    ushort phx = f2b(pqx), phy = f2b(pqy), phz = f2b(pqz);
    Ko[96]  = phx; Ko[97]  = f2b(pqx - b2f(phx)); Ko[98]  = phx;
    Ko[99]  = phy; Ko[100] = f2b(pqy - b2f(phy)); Ko[101] = phy;
    Ko[102] = phz; Ko[103] = f2b(pqz - b2f(phz)); Ko[104] = phz;
    float sq = pqx * pqx + pqy * pqy + pqz * pqz;
    ushort sqh = f2b(sq);
    Ko[105] = sqh; Ko[106] = f2b(sq - b2f(sqh));
    Ko[107] = 0x3F80; Ko[108] = 0x3F80; Ko[109] = 0; Ko[110] = 0; Ko[111] = 0;

    // Q-side slots (pos_k of query node)
    ushort thx = f2b(pkx), thy = f2b(pky), thz = f2b(pkz);
    ushort qhx = f2b(-2.0f * b2f(thx)), qhy = f2b(-2.0f * b2f(thy)), qhz = f2b(-2.0f * b2f(thz));
    Qo[96]  = qhx; Qo[97]  = qhx; Qo[98]  = f2b(-2.0f * (pkx - b2f(thx)));
    Qo[99]  = qhy; Qo[100] = qhy; Qo[101] = f2b(-2.0f * (pky - b2f(thy)));
    Qo[102] = qhz; Qo[103] = qhz; Qo[104] = f2b(-2.0f * (pkz - b2f(thz)));
    Qo[105] = 0x3F80; Qo[106] = 0x3F80;
    float sk = pkx * pkx + pky * pky + pkz * pkz;
    ushort skh = f2b(sk);
    Qo[107] = skh; Qo[108] = f2b(sk - b2f(skh));
    Qo[109] = 0; Qo[110] = 0; Qo[111] = 0;

    // Vt derived rows
    ushort* Vc = Vt + (size_t)h * 144 * NN + n;
    Vc[(size_t)40 * NN] = 0x3F80;
    #pragma unroll
    for (int j = 41; j < 48; ++j) Vc[(size_t)j * NN] = 0;
    #pragma unroll
    for (int i = 0; i < 16; ++i) {
        float w = b2f(Vc[(size_t)(48 + 3 * i) * NN]) * pqx
                + b2f(Vc[(size_t)(49 + 3 * i) * NN]) * pqy
                + b2f(Vc[(size_t)(50 + 3 * i) * NN]) * pqz;
        Vc[(size_t)(96 + i) * NN] = f2b(w);
    }
    #pragma unroll
    for (int i = 0; i < 8; ++i) {
        float a = b2f(Vc[(size_t)(112 + i) * NN]);
        Vc[(size_t)(120 + 3 * i) * NN] = f2b(a * pqx);
        Vc[(size_t)(121 + 3 * i) * NN] = f2b(a * pqy);
        Vc[(size_t)(122 + 3 * i) * NN] = f2b(a * pqz);
    }
}

// ---------------------------------------------------------------------------
// Kernel C: MFMA attention. Block = 4 waves = (head, 32 queries); wave = 512 keys.
// S[n,m] and d2[n,m] via 16x16x16 bf16 MFMAs; p,g in VALU (poly exp + rsq);
// p,g repacked to bf16 feed value MFMAs directly (C-layout == B-layout chain).
// Cross-wave LDS tree reduce, then epilogue combines P/G parts and divides.
// ---------------------------------------------------------------------------
__global__ __launch_bounds__(256, 2) void attn_kernel(
    const ushort* __restrict__ Kf, const ushort* __restrict__ Qf,
    const ushort* __restrict__ Vt, const float* __restrict__ pos_k,
    const float* __restrict__ r0, float* __restrict__ out)
{
    const int bid = blockIdx.x;
    const int h   = bid & 7;              // head == XCD affinity
    const int m0  = (bid >> 3) * 32;
    const int t    = threadIdx.x;
    const int lane = t & 63, wid = t >> 6;
    const int l15  = lane & 15, lg = lane >> 4;

    const float r0h = r0[h], r0sq = r0h * r0h;

    // Q B-fragments (held in registers for the whole kernel)
    const ushort* Qp = Qf + ((size_t)h * NN + m0 + l15) * 128 + lg * 4;
    s4 qb[2][7];
    #pragma unroll
    for (int c = 0; c < 7; ++c) {
        qb[0][c] = *(const s4*)(Qp + c * 16);
        qb[1][c] = *(const s4*)(Qp + 16 * 128 + c * 16);
    }

    f4 acc[9][2];
    #pragma unroll
    for (int jb = 0; jb < 9; ++jb)
        #pragma unroll
        for (int mb = 0; mb < 2; ++mb)
            acc[jb][mb] = (f4){0.f, 0.f, 0.f, 0.f};

    const ushort* kp = Kf + ((size_t)h * NN + wid * 512 + l15) * 128 + lg * 4;
    const ushort* vp = Vt + ((size_t)h * 144 + l15) * NN + wid * 512 + lg * 4;

    for (int it = 0; it < 32; ++it) {
        s4 ka[7], va[9];
        #pragma unroll
        for (int c = 0; c < 7; ++c) ka[c] = *(const s4*)(kp + c * 16);
        #pragma unroll
        for (int jb = 0; jb < 9; ++jb) va[jb] = *(const s4*)(vp + (size_t)jb * 16 * NN);

        #pragma unroll
        for (int mb = 0; mb < 2; ++mb) {
            f4 dt = {0.f, 0.f, 0.f, 0.f}, dd = {0.f, 0.f, 0.f, 0.f};
            #pragma unroll
            for (int c = 0; c < 6; ++c) dt = mfma16(ka[c], qb[mb][c], dt);
            dd = mfma16(ka[6], qb[mb][6], dd);

            float p[4], g[4];
            #pragma unroll
            for (int r = 0; r < 4; ++r) {
                float x  = r0sq + dd[r];
                float rs = __builtin_amdgcn_rsqf(x);     // 1/sqrt(r0^2+d2)
                float tt = rs * rs;                      // 1/(r0^2+d2)
                float y  = dt[r];                        // 0.1*dot (scale folded in Qf)
                float e  = fmaf(y, fmaf(0.5f, y, 1.0f), 1.0f);   // exp(y), |y|<0.005
                p[r] = r0sq * tt * e;
                g[r] = p[r] * rs;
            }
            s4 pb = pack4(p[0], p[1], p[2], p[3]);
            s4 gb = pack4(g[0], g[1], g[2], g[3]);
            #pragma unroll
            for (int jb = 0; jb < 3; ++jb) acc[jb][mb] = mfma16(va[jb], pb, acc[jb][mb]);
            #pragma unroll
            for (int jb = 3; jb < 9; ++jb) acc[jb][mb] = mfma16(va[jb], gb, acc[jb][mb]);
        }
        kp += 16 * 128;
        vp += 16;
    }

    // ---- cross-wave reduction ----
    __shared__ float buf[2][64][73];
    float my[72];
    #pragma unroll
    for (int jb = 0; jb < 9; ++jb)
        #pragma unroll
        for (int mb = 0; mb < 2; ++mb)
            #pragma unroll
            for (int r = 0; r < 4; ++r)
                my[(jb * 2 + mb) * 4 + r] = acc[jb][mb][r];

    if (wid >= 2) {
        float* p = &buf[wid - 2][lane][0];
        #pragma unroll
        for (int i = 0; i < 72; ++i) p[i] = my[i];
    }
    __syncthreads();
    if (wid < 2) {
        const float* p = &buf[wid][lane][0];
        #pragma unroll
        for (int i = 0; i < 72; ++i) my[i] += p[i];
    }
    __syncthreads();
    if (wid == 1) {
        float* p = &buf[0][lane][0];
        #pragma unroll
        for (int i = 0; i < 72; ++i) p[i] = my[i];
    }
    __syncthreads();
    float* red = &buf[0][0][0];               // 144*33 floats, aliases buf
    if (wid == 0) {
        const float* p = &buf[0][lane][0];
        #pragma unroll
        for (int i = 0; i < 72; ++i) my[i] += p[i];
        #pragma unroll
        for (int jb = 0; jb < 9; ++jb)
            #pragma unroll
            for (int mb = 0; mb < 2; ++mb)
                #pragma unroll
                for (int r = 0; r < 4; ++r)
                    red[(jb * 16 + lg * 4 + r) * 33 + mb * 16 + l15] = my[(jb * 2 + mb) * 4 + r];
    }
    __syncthreads();

    // ---- epilogue: 256 threads, thread t -> (m = m0 + t&31, 5 outputs) ----
    {
        int ml = t & 31, task = t >> 5;
        int m = m0 + ml;
        float pk0 = pos_k[m * 3], pk1 = pos_k[m * 3 + 1], pk2 = pos_k[m * 3 + 2];
        float inv = 1.0f / red[40 * 33 + ml];
        #pragma unroll
        for (int oo = 0; oo < 5; ++oo) {
            int o = task * 5 + oo;
            if (o < 16) {
                int i = o;
                float val = red[i * 33 + ml]
                          + pk0 * red[(48 + 3 * i) * 33 + ml]
                          + pk1 * red[(49 + 3 * i) * 33 + ml]
                          + pk2 * red[(50 + 3 * i) * 33 + ml]
                          - red[(96 + i) * 33 + ml];
                out[(size_t)m * 128 + h * 16 + i] = val * inv;
            } else {
                int q = o - 16, ip = q / 3, v = q - 3 * ip;
                float pkv = (v == 0) ? pk0 : ((v == 1) ? pk1 : pk2);
                float val = red[(16 + q) * 33 + ml]
                          + pkv * red[(112 + ip) * 33 + ml]
                          - red[(120 + q) * 33 + ml];
                out[(size_t)NN * 128 + (size_t)m * 192 + h * 24 + q] = val * inv;
            }
        }
    }
}

extern "C" void kernel_launch(void* const* d_in, const int* in_sizes, int n_in,
                              void* d_out, int out_size, void* d_ws, size_t ws_size,
                              hipStream_t stream) {
    const float* ax       = (const float*)d_in[0];
    const float* vx       = (const float*)d_in[1];
    const float* pos_k    = (const float*)d_in[2];
    const float* pos_q    = (const float*)d_in[3];
    const float* r0       = (const float*)d_in[4];
    const float* W_ak     = (const float*)d_in[5];
    const float* W_vk     = (const float*)d_in[6];
    const float* W_aq     = (const float*)d_in[7];
    const float* W_vq     = (const float*)d_in[8];
    const float* W_aval   = (const float*)d_in[9];
    const float* W_vval   = (const float*)d_in[10];
    const float* W_a2vval = (const float*)d_in[11];
    const float* W_v2aval = (const float*)d_in[12];

    ushort* Kf = (ushort*)d_ws;                       // 8*2048*128
    ushort* Qf = Kf + (size_t)NH * NN * 128;          // 8*2048*128
    ushort* Vt = Qf + (size_t)NH * NN * 128;          // 8*144*2048
    float*  outp = (float*)d_out;

    hipLaunchKernelGGL(proj_kernel, dim3(NN / 8), dim3(256), 0, stream,
                       ax, vx, W_ak, W_vk, W_aq, W_vq, W_aval, W_vval,
                       W_a2vval, W_v2aval, Kf, Qf, Vt);
    hipLaunchKernelGGL(finish_kernel, dim3(64), dim3(256), 0, stream,
                       pos_k, pos_q, Kf, Qf, Vt);
    hipLaunchKernelGGL(attn_kernel, dim3(64 * NH), dim3(256), 0, stream,
                       Kf, Qf, Vt, pos_k, r0, outp);
}

// Round 3
// 122.401 us; speedup vs baseline: 3.5319x; 1.4290x over previous
//
#include <hip/hip_runtime.h>

#define NN 2048
#define NH 8

typedef __attribute__((ext_vector_type(4))) short s4;
typedef __attribute__((ext_vector_type(8))) short s8;
typedef __attribute__((ext_vector_type(4))) float f4;

static __device__ __forceinline__ ushort f2b(float x) {
    uint u = __builtin_bit_cast(uint, x);
    uint r = (u + 0x7FFFu + ((u >> 16) & 1u)) >> 16;
    return (ushort)r;
}
static __device__ __forceinline__ float b2f(ushort b) {
    return __builtin_bit_cast(float, ((uint)b) << 16);
}
static __device__ __forceinline__ uint cvtpk(float lo, float hi) {
    uint r;
    asm("v_cvt_pk_bf16_f32 %0, %1, %2" : "=v"(r) : "v"(lo), "v"(hi));
    return r;
}
static __device__ __forceinline__ s4 pack4(float a, float b, float c, float d) {
    uint2 w; w.x = cvtpk(a, b); w.y = cvtpk(c, d);
    return __builtin_bit_cast(s4, w);
}
static __device__ __forceinline__ f4 mfma16(s4 a, s4 b, f4 c) {
#if __has_builtin(__builtin_amdgcn_mfma_f32_16x16x16bf16_1k)
    return __builtin_amdgcn_mfma_f32_16x16x16bf16_1k(a, b, c, 0, 0, 0);
#else
    asm("v_mfma_f32_16x16x16_bf16 %0, %1, %2, %0" : "+v"(c) : "v"(a), "v"(b));
    return c;
#endif
}
static __device__ __forceinline__ f4 mfma32(s8 a, s8 b, f4 c) {
#if __has_builtin(__builtin_amdgcn_mfma_f32_16x16x32_bf16)
    return __builtin_amdgcn_mfma_f32_16x16x32_bf16(a, b, c, 0, 0, 0);
#else
    asm("v_mfma_f32_16x16x32_bf16 %0, %1, %2, %0" : "+v"(c) : "v"(a), "v"(b));
    return c;
#endif
}

// ---------------------------------------------------------------------------
// Kernel A: projections.
// Kf[h][n][128]: [0..31]=ak, [32+s]=vk, [80..95]=0, [96..127]=d2 slots (finish)
// Qf[h][m][128]: same with 0.1*aq, 0.1*vq
// Vn[h][n][152] node-major RAW: [0..15]=aval, [16+s]=vval, [48+s]=v2a, [112+i]=a2v
// ---------------------------------------------------------------------------
__global__ __launch_bounds__(256) void proj_kernel(
    const float* __restrict__ ax, const float* __restrict__ vx,
    const float* __restrict__ W_ak, const float* __restrict__ W_vk,
    const float* __restrict__ W_aq, const float* __restrict__ W_vq,
    const float* __restrict__ W_aval, const float* __restrict__ W_vval,
    const float* __restrict__ W_a2vval, const float* __restrict__ W_v2aval,
    ushort* __restrict__ Kf, ushort* __restrict__ Qf, ushort* __restrict__ Vn)
{
    __shared__ float axs[8][128];
    __shared__ float vxs[3][8][64];
    const int t  = threadIdx.x;
    const int n0 = blockIdx.x * 8;

    for (int idx = t; idx < 8 * 128; idx += 256)
        axs[idx >> 7][idx & 127] = ax[n0 * 128 + idx];
    for (int idx = t; idx < 8 * 192; idx += 256) {
        int nb = idx / 192, r = idx - nb * 192;
        int j = r / 3, v = r - j * 3;
        vxs[v][nb][j] = vx[n0 * 192 + idx];
    }
    __syncthreads();

    #pragma unroll 1
    for (int rr = 0; rr < 8; ++rr) {
        int r = rr * 256 + t;
        const float* wrow; int h, v = 0, col = 0, vrow = -1; bool isA;
        float scale = 1.0f; ushort* dst = nullptr;
        if (r < 256)       { int q = r;        h = q >> 5; wrow = W_ak     + q * 128;               isA = true;  dst = Kf; col = q & 31; }
        else if (r < 512)  { int q = r - 256;  h = q >> 5; wrow = W_aq     + q * 128;               isA = true;  dst = Qf; col = q & 31; scale = 0.1f; }
        else if (r < 896)  { int q = r - 512;  h = q / 48; int s = q - h * 48; v = s % 3; wrow = W_vk     + (h * 16 + s / 3) * 64; isA = false; dst = Kf; col = 32 + s; }
        else if (r < 1280) { int q = r - 896;  h = q / 48; int s = q - h * 48; v = s % 3; wrow = W_vq     + (h * 16 + s / 3) * 64; isA = false; dst = Qf; col = 32 + s; scale = 0.1f; }
        else if (r < 1408) { int q = r - 1280; h = q >> 4; wrow = W_aval   + q * 128;               isA = true;  vrow = q & 15; }
        else if (r < 1600) { int q = r - 1408; h = q / 24; int s = q - h * 24; v = s % 3; wrow = W_vval   + (h * 8  + s / 3) * 64; isA = false; vrow = 16 + s; }
        else if (r < 1984) { int q = r - 1600; h = q / 48; int s = q - h * 48; v = s % 3; wrow = W_v2aval + (h * 16 + s / 3) * 64; isA = false; vrow = 48 + s; }
        else               { int q = r - 1984; h = q >> 3; wrow = W_a2vval + q * 128;               isA = true;  vrow = 112 + (q & 7); }

        float acc[8] = {0.f, 0.f, 0.f, 0.f, 0.f, 0.f, 0.f, 0.f};
        if (isA) {
            for (int j = 0; j < 128; j += 4) {
                float4 w4 = *(const float4*)(wrow + j);
                #pragma unroll
                for (int nb = 0; nb < 8; ++nb) {
                    float4 x4 = *(const float4*)(&axs[nb][j]);
                    acc[nb] += w4.x * x4.x + w4.y * x4.y + w4.z * x4.z + w4.w * x4.w;
                }
            }
        } else {
            for (int j = 0; j < 64; j += 4) {
                float4 w4 = *(const float4*)(wrow + j);
                #pragma unroll
                for (int nb = 0; nb < 8; ++nb) {
                    float4 x4 = *(const float4*)(&vxs[v][nb][j]);
                    acc[nb] += w4.x * x4.x + w4.y * x4.y + w4.z * x4.z + w4.w * x4.w;
                }
            }
        }
        #pragma unroll
        for (int nb = 0; nb < 8; ++nb) {
            ushort bv = f2b(scale * acc[nb]);
            if (vrow >= 0) Vn[((size_t)h * NN + n0 + nb) * 152 + vrow] = bv;
            else           dst[((size_t)h * NN + n0 + nb) * 128 + col] = bv;
        }
    }
}

// ---------------------------------------------------------------------------
// Kernel B: d2 slot channels + zero pads in Kf/Qf. Thread per (h, n).
// ---------------------------------------------------------------------------
__global__ __launch_bounds__(256) void finish_kernel(
    const float* __restrict__ pos_k, const float* __restrict__ pos_q,
    ushort* __restrict__ Kf, ushort* __restrict__ Qf)
{
    int g = blockIdx.x * 256 + threadIdx.x;
    int h = g >> 11, n = g & 2047;
    float pqx = pos_q[n * 3], pqy = pos_q[n * 3 + 1], pqz = pos_q[n * 3 + 2];
    float pkx = pos_k[n * 3], pky = pos_k[n * 3 + 1], pkz = pos_k[n * 3 + 2];

    ushort* Ko = Kf + ((size_t)h * NN + n) * 128;
    ushort* Qo = Qf + ((size_t)h * NN + n) * 128;
    #pragma unroll
    for (int j = 80; j < 96; ++j) { Ko[j] = 0; Qo[j] = 0; }
    #pragma unroll
    for (int j = 112; j < 128; ++j) { Ko[j] = 0; Qo[j] = 0; }

    ushort phx = f2b(pqx), phy = f2b(pqy), phz = f2b(pqz);
    Ko[96]  = phx; Ko[97]  = f2b(pqx - b2f(phx)); Ko[98]  = phx;
    Ko[99]  = phy; Ko[100] = f2b(pqy - b2f(phy)); Ko[101] = phy;
    Ko[102] = phz; Ko[103] = f2b(pqz - b2f(phz)); Ko[104] = phz;
    float sq = pqx * pqx + pqy * pqy + pqz * pqz;
    ushort sqh = f2b(sq);
    Ko[105] = sqh; Ko[106] = f2b(sq - b2f(sqh));
    Ko[107] = 0x3F80; Ko[108] = 0x3F80; Ko[109] = 0; Ko[110] = 0; Ko[111] = 0;

    ushort thx = f2b(pkx), thy = f2b(pky), thz = f2b(pkz);
    ushort qhx = f2b(-2.0f * b2f(thx)), qhy = f2b(-2.0f * b2f(thy)), qhz = f2b(-2.0f * b2f(thz));
    Qo[96]  = qhx; Qo[97]  = qhx; Qo[98]  = f2b(-2.0f * (pkx - b2f(thx)));
    Qo[99]  = qhy; Qo[100] = qhy; Qo[101] = f2b(-2.0f * (pky - b2f(thy)));
    Qo[102] = qhz; Qo[103] = qhz; Qo[104] = f2b(-2.0f * (pkz - b2f(thz)));
    Qo[105] = 0x3F80; Qo[106] = 0x3F80;
    float sk = pkx * pkx + pky * pky + pkz * pkz;
    ushort skh = f2b(sk);
    Qo[107] = skh; Qo[108] = f2b(sk - b2f(skh));
    Qo[109] = 0; Qo[110] = 0; Qo[111] = 0;
}

// ---------------------------------------------------------------------------
// Kernel C: transpose + derived value rows.
// Vn[h][n][152] node-major -> Vt[h][144][2048] feature-major.
// Rows: [0..15]=aval,[16..39]=vval,[40]=1,[41..47]=0,[48..95]=v2a,
//       [96+i]=v2a_i.pq, [112..119]=a2v, [120+3i+v]=a2v_i*pq_v
// ---------------------------------------------------------------------------
__global__ __launch_bounds__(256) void vtrans_kernel(
    const ushort* __restrict__ Vn, const float* __restrict__ pos_q,
    ushort* __restrict__ Vt)
{
    __shared__ ushort lds_n[64 * 160];
    __shared__ float lds_pq[192];
    const int bid = blockIdx.x;
    const int h = bid & 7, n0 = (bid >> 3) * 64;
    const int t = threadIdx.x;

    const ushort* src = Vn + ((size_t)h * NN + n0) * 152;
    #pragma unroll
    for (int p = 0; p < 5; ++p) {
        int idx = p * 256 + t;
        if (idx < 1216) {
            int node = idx / 19, ch = idx - node * 19;
            *(uint4*)(&lds_n[node * 160 + ch * 8]) =
                *(const uint4*)(src + (size_t)node * 152 + ch * 8);
        }
    }
    if (t < 192) lds_pq[t] = pos_q[n0 * 3 + t];
    __syncthreads();

    #pragma unroll 1
    for (int p = 0; p < 5; ++p) {
        int fi = p * 32 + (t >> 3);
        if (fi < 144) {
            int nb0 = (t & 7) * 8;
            uint rr[4];
            #pragma unroll
            for (int e = 0; e < 8; ++e) {
                int node = nb0 + e;
                const ushort* row = lds_n + node * 160;
                ushort bv;
                if (fi < 40 || (fi >= 48 && fi < 96) || (fi >= 112 && fi < 120)) {
                    bv = row[fi];
                } else if (fi < 48) {
                    bv = (fi == 40) ? (ushort)0x3F80 : (ushort)0;
                } else if (fi < 112) {
                    int i = fi - 96;
                    float val = b2f(row[48 + 3 * i]) * lds_pq[node * 3 + 0]
                              + b2f(row[49 + 3 * i]) * lds_pq[node * 3 + 1]
                              + b2f(row[50 + 3 * i]) * lds_pq[node * 3 + 2];
                    bv = f2b(val);
                } else {
                    int s = fi - 120, ip = s / 3, v = s - 3 * ip;
                    bv = f2b(b2f(row[112 + ip]) * lds_pq[node * 3 + v]);
                }
                if ((e & 1) == 0) rr[e >> 1] = bv;
                else              rr[e >> 1] |= ((uint)bv) << 16;
            }
            uint4 outw; outw.x = rr[0]; outw.y = rr[1]; outw.z = rr[2]; outw.w = rr[3];
            *(uint4*)(Vt + ((size_t)h * 144 + fi) * NN + n0 + nb0) = outw;
        }
    }
}

// ---------------------------------------------------------------------------
// Kernel D: attention. Grid 256 = 32 m-blocks x 8 heads; block 256 = 4 waves.
// Wave = 16 queries (query-split, no reduction); all waves share LDS-staged
// K/V tiles of 32 keys, double-buffered, XOR-swizzled for bank-uniform reads.
// QK+d2 via mfma 16x16x32 (self-consistent channel map); values via x16 chain.
// ---------------------------------------------------------------------------
__global__ __launch_bounds__(256, 1) void attn_kernel(
    const ushort* __restrict__ Kf, const ushort* __restrict__ Qf,
    const ushort* __restrict__ Vt, const float* __restrict__ pos_k,
    const float* __restrict__ r0, float* __restrict__ out)
{
    __shared__ __align__(16) char smem[39168];   // 2x(8K K-tile + 9K V-tile); epilogue: red[4][144][17]f32
    const int bid = blockIdx.x;
    const int h = bid & 7;
    const int m0 = (bid >> 3) * 64;
    const int t = threadIdx.x;
    const int lane = t & 63, w = t >> 6;
    const int l15 = lane & 15, lg = lane >> 4;

    const float r0h = r0[h], r0sq = r0h * r0h;
    const ushort* Kg = Kf + (size_t)h * NN * 128;
    const ushort* Vg = Vt + (size_t)h * 144 * NN;

    // Q fragments, channel map chan = c*32 + lg*8 + j (same map used for ka)
    const ushort* Qp = Qf + ((size_t)h * NN + m0 + w * 16 + l15) * 128 + lg * 8;
    const s8 qb0 = *(const s8*)(Qp);
    const s8 qb1 = *(const s8*)(Qp + 32);
    const s8 qb2 = *(const s8*)(Qp + 64);
    const s8 qb3 = *(const s8*)(Qp + 96);

    f4 acc[9];
    #pragma unroll
    for (int jb = 0; jb < 9; ++jb) acc[jb] = (f4){0.f, 0.f, 0.f, 0.f};

    uint4 kreg0, kreg1, vreg0, vreg1, vreg2;
    const int kt = t >> 4, kc = (t & 15) * 8;     // K stage: key row, chan (shorts)
    const int vf = t >> 2, vc = (t & 3) * 8;      // V stage: feature row, key (shorts)
    const int kws0 = kt * 256 + ((kc * 2) ^ ((kt & 7) << 4));
    const int kws1 = (kt + 16) * 256 + ((kc * 2) ^ ((kt & 7) << 4));
    const int vws0 = vf * 64 + ((vc * 2) ^ ((vf & 3) << 4));
    const int vws1 = (vf + 64) * 64 + ((vc * 2) ^ ((vf & 3) << 4));
    const int vws2 = (vf + 128) * 64 + ((vc * 2) ^ ((vf & 3) << 4));

#define LOAD_TILE(k0)                                                               \
    kreg0 = *(const uint4*)(Kg + (size_t)((k0) + kt) * 128 + kc);                   \
    kreg1 = *(const uint4*)(Kg + (size_t)((k0) + 16 + kt) * 128 + kc);              \
    vreg0 = *(const uint4*)(Vg + (size_t)vf * NN + (k0) + vc);                      \
    vreg1 = *(const uint4*)(Vg + (size_t)(vf + 64) * NN + (k0) + vc);               \
    if (t < 64) vreg2 = *(const uint4*)(Vg + (size_t)(vf + 128) * NN + (k0) + vc);

#define WRITE_TILE(b)                                                               \
  { char* kb_ = smem + (b) * 17408; char* vb_ = kb_ + 8192;                         \
    *(uint4*)(kb_ + kws0) = kreg0;  *(uint4*)(kb_ + kws1) = kreg1;                  \
    *(uint4*)(vb_ + vws0) = vreg0;  *(uint4*)(vb_ + vws1) = vreg1;                  \
    if (t < 64) *(uint4*)(vb_ + vws2) = vreg2; }

#define COMPUTE_TILE(b)                                                             \
  { const char* kb_ = smem + (b) * 17408; const char* vb_ = kb_ + 8192;             \
    _Pragma("unroll")                                                               \
    for (int kg = 0; kg < 2; ++kg) {                                                \
      const char* kr = kb_ + (kg * 16 + l15) * 256;                                 \
      const int kx = (l15 & 7) << 4;                                                \
      s8 ka0 = *(const s8*)(kr + ((lg * 16      ) ^ kx));                           \
      s8 ka1 = *(const s8*)(kr + ((lg * 16 +  64) ^ kx));                           \
      s8 ka2 = *(const s8*)(kr + ((lg * 16 + 128) ^ kx));                           \
      s8 ka3 = *(const s8*)(kr + ((lg * 16 + 192) ^ kx));                           \
      f4 z = (f4){0.f, 0.f, 0.f, 0.f};                                              \
      f4 dt = mfma32(ka0, qb0, z);                                                  \
      dt = mfma32(ka1, qb1, dt);                                                    \
      dt = mfma32(ka2, qb2, dt);                                                    \
      f4 dd = mfma32(ka3, qb3, z);                                                  \
      float pv[4], gv[4];                                                           \
      _Pragma("unroll")                                                             \
      for (int r = 0; r < 4; ++r) {                                                 \
        float x = r0sq + dd[r];                                                     \
        float rs = __builtin_amdgcn_rsqf(x);                                        \
        float tt = rs * rs;                                                         \
        float y = dt[r];                                                            \
        float e = fmaf(y, fmaf(0.5f, y, 1.0f), 1.0f);                               \
        pv[r] = r0sq * tt * e;                                                      \
        gv[r] = pv[r] * rs;                                                         \
      }                                                                             \
      s4 pb = pack4(pv[0], pv[1], pv[2], pv[3]);                                    \
      s4 gb = pack4(gv[0], gv[1], gv[2], gv[3]);                                    \
      const char* vr = vb_ + l15 * 64;                                              \
      const int vx = ((kg * 32 + lg * 8) ^ ((l15 & 3) << 4));                       \
      _Pragma("unroll")                                                             \
      for (int jb = 0; jb < 3; ++jb)                                                \
        acc[jb] = mfma16(*(const s4*)(vr + jb * 1024 + vx), pb, acc[jb]);           \
      _Pragma("unroll")                                                             \
      for (int jb = 3; jb < 9; ++jb)                                                \
        acc[jb] = mfma16(*(const s4*)(vr + jb * 1024 + vx), gb, acc[jb]);           \
    } }

    LOAD_TILE(0)
    WRITE_TILE(0)
    __syncthreads();
    #pragma unroll 2
    for (int tile = 0; tile < 64; ++tile) {
        int b = tile & 1;
        if (tile < 63) { LOAD_TILE((tile + 1) * 32) }
        COMPUTE_TILE(b)
        __syncthreads();
        if (tile < 63) { WRITE_TILE(b ^ 1) }
        __syncthreads();
    }

    // ---- dump per-wave accumulators and combine ----
    float* red = (float*)smem;
    {
        float* rp = red + (w * 144) * 17;
        #pragma unroll
        for (int jb = 0; jb < 9; ++jb)
            #pragma unroll
            for (int r = 0; r < 4; ++r)
                rp[(jb * 16 + lg * 4 + r) * 17 + l15] = acc[jb][r];
    }
    __syncthreads();
    {
        const int w2 = t >> 6, lq = (t & 63) >> 2, part = t & 3;
        const int m = m0 + w2 * 16 + lq;
        const float* R = red + (w2 * 144) * 17 + lq;
        const float inv = 1.0f / R[40 * 17];
        const float pk0 = pos_k[m * 3], pk1 = pos_k[m * 3 + 1], pk2 = pos_k[m * 3 + 2];
        float* oa = out + (size_t)m * 128 + h * 16;
        #pragma unroll
        for (int ii = 0; ii < 4; ++ii) {
            int i = part * 4 + ii;
            float v = R[i * 17] + pk0 * R[(48 + 3 * i) * 17] + pk1 * R[(49 + 3 * i) * 17]
                    + pk2 * R[(50 + 3 * i) * 17] - R[(96 + i) * 17];
            oa[i] = v * inv;
        }
        float* ov = out + (size_t)NN * 128 + (size_t)m * 192 + h * 24;
        #pragma unroll
        for (int ss = 0; ss < 6; ++ss) {
            int s = part * 6 + ss;
            int ip = s / 3, v3 = s - 3 * ip;
            float pkv = (v3 == 0) ? pk0 : ((v3 == 1) ? pk1 : pk2);
            float v = R[(16 + s) * 17] + pkv * R[(112 + ip) * 17] - R[(120 + s) * 17];
            ov[s] = v * inv;
        }
    }
#undef LOAD_TILE
#undef WRITE_TILE
#undef COMPUTE_TILE
}

extern "C" void kernel_launch(void* const* d_in, const int* in_sizes, int n_in,
                              void* d_out, int out_size, void* d_ws, size_t ws_size,
                              hipStream_t stream) {
    const float* ax       = (const float*)d_in[0];
    const float* vx       = (const float*)d_in[1];
    const float* pos_k    = (const float*)d_in[2];
    const float* pos_q    = (const float*)d_in[3];
    const float* r0       = (const float*)d_in[4];
    const float* W_ak     = (const float*)d_in[5];
    const float* W_vk     = (const float*)d_in[6];
    const float* W_aq     = (const float*)d_in[7];
    const float* W_vq     = (const float*)d_in[8];
    const float* W_aval   = (const float*)d_in[9];
    const float* W_vval   = (const float*)d_in[10];
    const float* W_a2vval = (const float*)d_in[11];
    const float* W_v2aval = (const float*)d_in[12];

    ushort* Kf = (ushort*)d_ws;                        // 8*2048*128
    ushort* Qf = Kf + (size_t)NH * NN * 128;           // 8*2048*128
    ushort* Vn = Qf + (size_t)NH * NN * 128;           // 8*2048*152
    ushort* Vt = Vn + (size_t)NH * NN * 152;           // 8*144*2048
    float*  outp = (float*)d_out;

    hipLaunchKernelGGL(proj_kernel, dim3(NN / 8), dim3(256), 0, stream,
                       ax, vx, W_ak, W_vk, W_aq, W_vq, W_aval, W_vval,
                       W_a2vval, W_v2aval, Kf, Qf, Vn);
    hipLaunchKernelGGL(finish_kernel, dim3(64), dim3(256), 0, stream,
                       pos_k, pos_q, Kf, Qf);
    hipLaunchKernelGGL(vtrans_kernel, dim3(32 * NH), dim3(256), 0, stream,
                       Vn, pos_q, Vt);
    hipLaunchKernelGGL(attn_kernel, dim3(32 * NH), dim3(256), 0, stream,
                       Kf, Qf, Vt, pos_k, r0, outp);
}